// Round 9
// baseline (259.345 us; speedup 1.0000x reference)
//
#include <hip/hip_runtime.h>
#include <math.h>

// Problem constants (match reference)
#define NNODES 50000
#define NEDGES 800000
#define INF 128
#define OUTF 128
#define HEADS 2
#define NEG_SLOPE 0.2f

// Hybrid XCD-local binning:
//  - primary: per-(node, xcd) sub-bin of 4 slots; slot reserved via a
//    WORKGROUP-scope atomic on an XCD-private cursor -> executes in the local
//    XCD's L2 (no Infinity-Fabric RMW; r8 showed 800k device atomics ~= 55us
//    throughput wall). Per-XCD regions are 64B-exclusive (N = 16*3125).
//  - secondary: shared per-node 16-slot bin via device-scope atomic
//    (per-XCD deg ~ Poisson(2) -> P(>4) ~ 3.6% -> ~29k device atomics, 27x fewer).
//  - exact overflow list beyond that (any distribution stays correct).
#define NXCD 8
#define PCAP 4           // primary slots per (node, xcd)
#define SCAPS 16         // secondary slots per node
#define OVFCAP 32768

__device__ __forceinline__ unsigned short f2bf(float f) {
    unsigned u = __float_as_uint(f);
    unsigned r = (u + 0x7FFFu + ((u >> 16) & 1u)) >> 16;   // RNE
    return (unsigned short)r;
}
__device__ __forceinline__ float bf2f(unsigned short b) {
    return __uint_as_float((unsigned)b << 16);
}
// 2x f32 -> packed bf16 (1 VALU op; T12 recipe)
__device__ __forceinline__ unsigned cvt_pk_bf16(float lo, float hi) {
    unsigned r;
    asm("v_cvt_pk_bf16_f32 %0, %1, %2" : "=v"(r) : "v"(lo), "v"(hi));
    return r;
}

typedef __attribute__((ext_vector_type(8))) short frag_ab;   // 8 bf16 (4 VGPRs)
typedef __attribute__((ext_vector_type(4))) float frag_cd;   // 4 fp32 acc
typedef __attribute__((ext_vector_type(8))) unsigned short ushort8v;

#define APITCH 136   // halfs per padded LDS row (272 B)

// ---------- K0: one-time param prep (9 blocks) ----------
__global__ void init_kernel(const float* __restrict__ W,
                            const float* __restrict__ attn_l,
                            const float* __restrict__ attn_r,
                            unsigned short* __restrict__ Wb,
                            float* __restrict__ wfold) {
    const int b = blockIdx.x, t = threadIdx.x;
    if (b == 0) {
        // el[n,h] = feat[n]·wfold[h], er[n,h] = feat[n]·wfold[2+h]
        int h = t >> 7, f = t & 127;
        float sl = 0.f, sr = 0.f;
#pragma unroll 16
        for (int o = 0; o < 128; ++o) {
            float wv = W[(size_t)(h * 128 + o) * 128 + f];
            sl = fmaf(attn_l[h * 128 + o], wv, sl);
            sr = fmaf(attn_r[h * 128 + o], wv, sr);
        }
        wfold[h * 128 + f] = sl;
        wfold[(2 + h) * 128 + f] = sr;
        return;
    }
    int base = (b - 1) * 4096 + t * 16;
#pragma unroll
    for (int q = 0; q < 4; ++q) {
        float4 g = *(const float4*)(W + base + q * 4);
        ushort4 v; v.x = f2bf(g.x); v.y = f2bf(g.y); v.z = f2bf(g.z); v.w = f2bf(g.w);
        *(ushort4*)(Wb + base + q * 4) = v;
    }
}

// ---------- K1: el/er projection + cursor zeroing (curx 8N + scur N + ovfcnt) ----------
__global__ __launch_bounds__(256) void prep_kernel(const float* __restrict__ feat,
                                                   const float* __restrict__ wfold,
                                                   float* __restrict__ el,
                                                   float* __restrict__ er,
                                                   int* __restrict__ curx, int N) {
    const int t = threadIdx.x;
    const int gtid = blockIdx.x * 256 + t;
    if (gtid < (NXCD + 1) * N + 1) curx[gtid] = 0;   // curx + scur + ovfcnt contiguous
    const int lid = t & 31;
    const int n = blockIdx.x * 8 + (t >> 5);
    if (n >= N) return;
    float4 f4 = *(const float4*)(feat + (size_t)n * INF + lid * 4);
    float pd[4];
#pragma unroll
    for (int vq = 0; vq < 4; ++vq) {
        float4 wv = *(const float4*)(wfold + vq * 128 + lid * 4);
        pd[vq] = f4.x * wv.x + f4.y * wv.y + f4.z * wv.z + f4.w * wv.w;
    }
#pragma unroll
    for (int m = 1; m < 32; m <<= 1)
#pragma unroll
        for (int vq = 0; vq < 4; ++vq) pd[vq] += __shfl_xor(pd[vq], m, 64);
    if (lid == 0) {
        *(float2*)(el + (size_t)n * 2) = make_float2(pd[0], pd[1]);
        *(float2*)(er + (size_t)n * 2) = make_float2(pd[2], pd[3]);
    }
}

// ---------- K2: wave-specialized fused gemm(ftb) || edge scatter ----------
// 512 threads: waves 0-3 gemm (r7-proven); waves 4-7 grid-stride edges with
// hybrid XCD-local slot reservation (see top comment).
__global__ __launch_bounds__(512) void fused_gemm_edge(
        const float* __restrict__ feat, const unsigned short* __restrict__ Wb,
        unsigned short* __restrict__ ftb,
        const float* __restrict__ el, const float* __restrict__ er,
        const float* __restrict__ e_w, const int* __restrict__ src,
        const int* __restrict__ dst, const float* __restrict__ attn_ew,
        int* __restrict__ curx, int* __restrict__ scur, int* __restrict__ ovfcnt,
        uint2* __restrict__ pbin, uint2* __restrict__ sbin, float4* __restrict__ ovf,
        int N, int E) {
    __shared__ unsigned short Bs[256 * APITCH];   // 69,632 B -> 2 blocks/CU
    const int t = threadIdx.x;
    const int lane = t & 63;
    const int m16 = lane & 15, quad = lane >> 4;
    const int n0 = blockIdx.x * 128;

    frag_ab af[2][4];
    bool vr0 = false, vr1 = false;
    int r0n = 0, r1n = 0;
    if (t < 256) {   // gemm waves: A-frag loads (overlap staging below)
        const int w = t >> 6;
        r0n = n0 + w * 16 + m16;
        r1n = r0n + 64;
        vr0 = r0n < N; vr1 = r1n < N;
#pragma unroll
        for (int kc = 0; kc < 4; ++kc) {
            const int cc = kc * 32 + quad * 8;
            float4 ga0 = make_float4(0.f, 0.f, 0.f, 0.f), ga1 = ga0;
            float4 gb0 = ga0, gb1 = ga0;
            if (vr0) {
                ga0 = *(const float4*)(feat + (size_t)r0n * INF + cc);
                ga1 = *(const float4*)(feat + (size_t)r0n * INF + cc + 4);
            }
            if (vr1) {
                gb0 = *(const float4*)(feat + (size_t)r1n * INF + cc);
                gb1 = *(const float4*)(feat + (size_t)r1n * INF + cc + 4);
            }
            union { int4 i; frag_ab f; } ua, ub;
            ua.i.x = (int)cvt_pk_bf16(ga0.x, ga0.y); ua.i.y = (int)cvt_pk_bf16(ga0.z, ga0.w);
            ua.i.z = (int)cvt_pk_bf16(ga1.x, ga1.y); ua.i.w = (int)cvt_pk_bf16(ga1.z, ga1.w);
            ub.i.x = (int)cvt_pk_bf16(gb0.x, gb0.y); ub.i.y = (int)cvt_pk_bf16(gb0.z, gb0.w);
            ub.i.z = (int)cvt_pk_bf16(gb1.x, gb1.y); ub.i.w = (int)cvt_pk_bf16(gb1.z, gb1.w);
            af[0][kc] = ua.f; af[1][kc] = ub.f;
        }
    }

    // stage Wb -> Bs, all 512 threads: 4096 16B-chunks, 8 per thread
#pragma unroll
    for (int i = 0; i < 8; ++i) {
        int q = t + i * 512;
        int row = q >> 4, c = q & 15;
        ushort8v v = *(const ushort8v*)(Wb + row * 128 + c * 8);
        *(ushort8v*)(&Bs[row * APITCH + c * 8]) = v;
    }
    __syncthreads();   // Bs ready (single, uniformly-executed barrier)

    if (t < 256) {
        // ---------------- gemm role ----------------
#pragma unroll 1
        for (int jt = 0; jt < 4; ++jt) {
            frag_cd acc[2][4];
#pragma unroll
            for (int rg = 0; rg < 2; ++rg)
#pragma unroll
                for (int nt = 0; nt < 4; ++nt) acc[rg][nt] = frag_cd{0.f, 0.f, 0.f, 0.f};
#pragma unroll
            for (int kc = 0; kc < 4; ++kc)
#pragma unroll
                for (int nt = 0; nt < 4; ++nt) {
                    frag_ab bf = *(const frag_ab*)(&Bs[(jt * 64 + nt * 16 + m16) * APITCH
                                                       + kc * 32 + quad * 8]);
                    acc[0][nt] = __builtin_amdgcn_mfma_f32_16x16x32_bf16(bf, af[0][kc],
                                                                         acc[0][nt], 0, 0, 0);
                    acc[1][nt] = __builtin_amdgcn_mfma_f32_16x16x32_bf16(bf, af[1][kc],
                                                                         acc[1][nt], 0, 0, 0);
                }
#pragma unroll
            for (int rg = 0; rg < 2; ++rg) {
                const int rr = rg ? r1n : r0n;
                if (rg ? vr1 : vr0) {
#pragma unroll
                    for (int nt = 0; nt < 4; ++nt) {
                        uint2 p;
                        p.x = cvt_pk_bf16(acc[rg][nt][0], acc[rg][nt][1]);
                        p.y = cvt_pk_bf16(acc[rg][nt][2], acc[rg][nt][3]);
                        *(uint2*)(ftb + (size_t)rr * 256 + jt * 64 + nt * 16 + quad * 4) = p;
                    }
                }
            }
        }
    } else {
        // ---------------- edge role: hybrid XCD-local scatter ----------------
        unsigned xcc;
        asm volatile("s_getreg_b32 %0, hwreg(HW_REG_XCC_ID)" : "=s"(xcc));
        xcc &= (NXCD - 1);
        const size_t cxb = (size_t)xcc * N;    // this XCD's private cursor/bin region
        const float aew0 = attn_ew[0], aew1 = attn_ew[1];
        const float aew2 = attn_ew[2], aew3 = attn_ew[3];
        const int stride = gridDim.x * 256;
        for (int e = blockIdx.x * 256 + (t - 256); e < E; e += stride) {
            int s = src[e], d = dst[e];
            float2 ew2 = *(const float2*)(e_w + (size_t)e * 2);
            float2 elv = *(const float2*)(el + (size_t)s * 2);
            float2 erv = *(const float2*)(er + (size_t)d * 2);
            float v0 = elv.x + erv.x + ew2.x * aew0 + ew2.y * aew1;
            float v1 = elv.y + erv.y + ew2.x * aew2 + ew2.y * aew3;
            v0 = v0 >= 0.f ? v0 : NEG_SLOPE * v0;
            v1 = v1 >= 0.f ? v1 : NEG_SLOPE * v1;
            float ee0 = __expf(v0);
            float ee1 = __expf(v1);
            unsigned pk = ((unsigned)f2bf(ee1) << 16) | (unsigned)f2bf(ee0);
            uint2 rec = make_uint2((unsigned)s, pk);
            // XCD-local reservation (plain L2 atomic, no fabric RMW)
            int pos = __hip_atomic_fetch_add(curx + cxb + d, 1,
                                             __ATOMIC_RELAXED, __HIP_MEMORY_SCOPE_WORKGROUP);
            if (pos < PCAP) {
                pbin[(cxb + d) * PCAP + pos] = rec;
            } else {
                int ps = atomicAdd(scur + d, 1);          // device scope (rare, ~3.6%)
                if (ps < SCAPS) {
                    sbin[(size_t)d * SCAPS + ps] = rec;
                } else {
                    int o = atomicAdd(ovfcnt, 1);
                    if (o < OVFCAP)
                        ovf[o] = make_float4(__int_as_float(d), __int_as_float(s), ee0, ee1);
                }
            }
        }
    }
}

// ---------- K3: wave-per-node gather-aggregate (r0 body over 8 sub-bins + secondary) ----------
__global__ __launch_bounds__(256) void aggregate(const unsigned short* __restrict__ ftb,
                                                 const float* __restrict__ feat,
                                                 const uint2* __restrict__ pbin,
                                                 const uint2* __restrict__ sbin,
                                                 const int* __restrict__ curx,
                                                 const int* __restrict__ scur,
                                                 const int* __restrict__ ovfcnt,
                                                 const float4* __restrict__ ovf,
                                                 float* __restrict__ out, int N) {
    const int t = threadIdx.x;
    const int w = t >> 6, l = t & 63;
    const int n = blockIdx.x * 4 + w;
    if (n >= N) return;
    const int c0 = 4 * l;            // this lane's 4 cols (0..252)
    const int h = l >> 5;            // lane's head
    // issue all 9 count loads up front (independent)
    int cx[NXCD];
#pragma unroll
    for (int x = 0; x < NXCD; ++x) cx[x] = curx[(size_t)x * N + n];
    const int scr = scur[n];

    float4 acc = make_float4(0.f, 0.f, 0.f, 0.f);
    float dn = 0.f;
#define BODY(RECEXPR)                                                          \
    {   uint2 rec = (RECEXPR);                                                 \
        int s = (int)rec.x;                                                    \
        float a = bf2f((unsigned short)(h ? (rec.y >> 16) : (rec.y & 0xFFFFu)));\
        dn += a;                                                               \
        ushort4 v = *(const ushort4*)(ftb + (size_t)s * 256 + c0);             \
        acc.x += a * bf2f(v.x);                                                \
        acc.y += a * bf2f(v.y);                                                \
        acc.z += a * bf2f(v.z);                                                \
        acc.w += a * bf2f(v.w);                                                \
    }
#pragma unroll
    for (int x = 0; x < NXCD; ++x) {
        const int cc = cx[x] < PCAP ? cx[x] : PCAP;
        const uint2* pb = pbin + ((size_t)x * N + n) * PCAP;
        for (int j = 0; j < cc; ++j) BODY(pb[j]);
    }
    {
        const int sc = scr < SCAPS ? scr : SCAPS;
        const uint2* sb = sbin + (size_t)n * SCAPS;
        for (int j = 0; j < sc; ++j) BODY(sb[j]);
    }
    if (scr > SCAPS) {   // exact overflow path (rare)
        int no = *ovfcnt; if (no > OVFCAP) no = OVFCAP;
        for (int i = 0; i < no; ++i) {
            float4 ov = ovf[i];
            if (__float_as_int(ov.x) == n) {
                int s = __float_as_int(ov.y);
                float a = h ? ov.w : ov.z;
                dn += a;
                ushort4 v = *(const ushort4*)(ftb + (size_t)s * 256 + c0);
                acc.x += a * bf2f(v.x);
                acc.y += a * bf2f(v.y);
                acc.z += a * bf2f(v.z);
                acc.w += a * bf2f(v.w);
            }
        }
    }
#undef BODY
    float inv = dn > 0.f ? 1.0f / dn : 0.f;
    float4 f4 = *(const float4*)(feat + (size_t)n * INF + (c0 & 127));
    float4 r;
    r.x = acc.x * inv + f4.x;
    r.y = acc.y * inv + f4.y;
    r.z = acc.z * inv + f4.z;
    r.w = acc.w * inv + f4.w;
    r.x = r.x > 0.f ? r.x : expm1f(r.x);
    r.y = r.y > 0.f ? r.y : expm1f(r.y);
    r.z = r.z > 0.f ? r.z : expm1f(r.z);
    r.w = r.w > 0.f ? r.w : expm1f(r.w);
    *(float4*)(out + (size_t)n * 256 + c0) = r;
}

extern "C" void kernel_launch(void* const* d_in, const int* in_sizes, int n_in,
                              void* d_out, int out_size, void* d_ws, size_t ws_size,
                              hipStream_t stream) {
    const float* feat    = (const float*)d_in[0];
    const float* e_w     = (const float*)d_in[1];
    const int*   src     = (const int*)d_in[2];
    const int*   dst     = (const int*)d_in[3];
    const float* W       = (const float*)d_in[4];
    const float* attn_l  = (const float*)d_in[5];
    const float* attn_r  = (const float*)d_in[6];
    const float* attn_ew = (const float*)d_in[7];
    float* out = (float*)d_out;

    const int N = in_sizes[0] / INF;   // 50000
    const int E = in_sizes[2];         // 800000

    // workspace carve-up (all offsets 64B-aligned for these sizes; ~48 MB)
    unsigned short* ftb = (unsigned short*)d_ws;                 // N*256 bf16   (25.6 MB)
    uint2*  pbin   = (uint2*)(ftb + (size_t)N * 256);            // 8*N*4 recs   (12.8 MB)
    uint2*  sbin   = pbin + (size_t)NXCD * N * PCAP;             // N*16 recs    (6.4 MB)
    float*  el     = (float*)(sbin + (size_t)N * SCAPS);         // N*2          (0.4 MB)
    float*  er     = el + (size_t)N * 2;                         // N*2          (0.4 MB)
    float*  wfold  = er + (size_t)N * 2;                         // 4*128 f      (2 KB)
    unsigned short* Wb = (unsigned short*)(wfold + 512);         // 256*128 bf16 (64 KB)
    float4* ovf    = (float4*)(Wb + 32768);                      // OVFCAP       (0.5 MB)
    int*    curx   = (int*)(ovf + OVFCAP);                       // 8N XCD-private (1.6 MB)
    int*    scur   = curx + (size_t)NXCD * N;                    // N secondary  (0.2 MB)
    int*    ovfcnt = scur + N;                                   // 1 (zeroed with curx)

    init_kernel<<<9, 256, 0, stream>>>(W, attn_l, attn_r, Wb, wfold);

    prep_kernel<<<(N + 7) / 8, 256, 0, stream>>>(feat, wfold, el, er, curx, N);

    fused_gemm_edge<<<(N + 127) / 128, 512, 0, stream>>>(feat, Wb, ftb, el, er, e_w,
                                                         src, dst, attn_ew,
                                                         curx, scur, ovfcnt,
                                                         pbin, sbin, ovf, N, E);

    aggregate<<<(N + 3) / 4, 256, 0, stream>>>(ftb, feat, pbin, sbin, curx, scur,
                                               ovfcnt, ovf, out, N);
}

// Round 10
// 215.657 us; speedup vs baseline: 1.2026x; 1.2026x over previous
//
#include <hip/hip_runtime.h>
#include <math.h>

// Problem constants (match reference)
#define NNODES 50000
#define NEDGES 800000
#define INF 128
#define OUTF 128
#define HEADS 2
#define NEG_SLOPE 0.2f

// Padded-bin CSR (r0/r8-proven): single cursor per node, CAP=32; overflow list.
// Cursor padded one-per-64B-line (neutral, kept from r8).
#define CAP 32
#define CSH 4            // cursor stride shift (16 ints = 64 B)
#define OVFCAP 32768

__device__ __forceinline__ unsigned short f2bf(float f) {
    unsigned u = __float_as_uint(f);
    unsigned r = (u + 0x7FFFu + ((u >> 16) & 1u)) >> 16;   // RNE
    return (unsigned short)r;
}
__device__ __forceinline__ float bf2f(unsigned short b) {
    return __uint_as_float((unsigned)b << 16);
}
// 2x f32 -> packed bf16 (1 VALU op; T12 recipe)
__device__ __forceinline__ unsigned cvt_pk_bf16(float lo, float hi) {
    unsigned r;
    asm("v_cvt_pk_bf16_f32 %0, %1, %2" : "=v"(r) : "v"(lo), "v"(hi));
    return r;
}

typedef __attribute__((ext_vector_type(8))) short frag_ab;   // 8 bf16 (4 VGPRs)
typedef __attribute__((ext_vector_type(4))) float frag_cd;   // 4 fp32 acc
typedef __attribute__((ext_vector_type(8))) unsigned short ushort8v;

#define APITCH 136   // halfs per padded LDS row (272 B)

// ---------- K0: one-time param prep (9 blocks) ----------
__global__ void init_kernel(const float* __restrict__ W,
                            const float* __restrict__ attn_l,
                            const float* __restrict__ attn_r,
                            unsigned short* __restrict__ Wb,
                            float* __restrict__ wfold) {
    const int b = blockIdx.x, t = threadIdx.x;
    if (b == 0) {
        // el[n,h] = feat[n]·wfold[h], er[n,h] = feat[n]·wfold[2+h]
        int h = t >> 7, f = t & 127;
        float sl = 0.f, sr = 0.f;
#pragma unroll 16
        for (int o = 0; o < 128; ++o) {
            float wv = W[(size_t)(h * 128 + o) * 128 + f];
            sl = fmaf(attn_l[h * 128 + o], wv, sl);
            sr = fmaf(attn_r[h * 128 + o], wv, sr);
        }
        wfold[h * 128 + f] = sl;
        wfold[(2 + h) * 128 + f] = sr;
        return;
    }
    int base = (b - 1) * 4096 + t * 16;
#pragma unroll
    for (int q = 0; q < 4; ++q) {
        float4 g = *(const float4*)(W + base + q * 4);
        ushort4 v; v.x = f2bf(g.x); v.y = f2bf(g.y); v.z = f2bf(g.z); v.w = f2bf(g.w);
        *(ushort4*)(Wb + base + q * 4) = v;
    }
}

// ---------- K1: el/er projection + padded-cursor zeroing (r8) ----------
__global__ __launch_bounds__(256) void prep_kernel(const float* __restrict__ feat,
                                                   const float* __restrict__ wfold,
                                                   float* __restrict__ el,
                                                   float* __restrict__ er,
                                                   int* __restrict__ cursor,
                                                   int* __restrict__ ovfcnt, int N) {
    const int t = threadIdx.x;
    const int gtid = blockIdx.x * 256 + t;
    if (gtid < (N << CSH)) cursor[gtid] = 0;
    if (gtid == 0) *ovfcnt = 0;
    const int lid = t & 31;
    const int n = blockIdx.x * 8 + (t >> 5);
    if (n >= N) return;
    float4 f4 = *(const float4*)(feat + (size_t)n * INF + lid * 4);
    float pd[4];
#pragma unroll
    for (int vq = 0; vq < 4; ++vq) {
        float4 wv = *(const float4*)(wfold + vq * 128 + lid * 4);
        pd[vq] = f4.x * wv.x + f4.y * wv.y + f4.z * wv.z + f4.w * wv.w;
    }
#pragma unroll
    for (int m = 1; m < 32; m <<= 1)
#pragma unroll
        for (int vq = 0; vq < 4; ++vq) pd[vq] += __shfl_xor(pd[vq], m, 64);
    if (lid == 0) {
        *(float2*)(el + (size_t)n * 2) = make_float2(pd[0], pd[1]);
        *(float2*)(er + (size_t)n * 2) = make_float2(pd[2], pd[3]);
    }
}

// shared edge-scatter body: processes edges [estart+off : ESTOP : stride]
__device__ __forceinline__ void edge_work(int e, int eend, int stride,
        const float* __restrict__ el, const float* __restrict__ er,
        const float* __restrict__ e_w, const int* __restrict__ src,
        const int* __restrict__ dst,
        float aew0, float aew1, float aew2, float aew3,
        int* __restrict__ cursor, int* __restrict__ ovfcnt,
        uint2* __restrict__ edata, float4* __restrict__ ovf) {
    for (; e < eend; e += stride) {
        int s = src[e], d = dst[e];
        float2 ew2 = *(const float2*)(e_w + (size_t)e * 2);
        float2 elv = *(const float2*)(el + (size_t)s * 2);
        float2 erv = *(const float2*)(er + (size_t)d * 2);
        float v0 = elv.x + erv.x + ew2.x * aew0 + ew2.y * aew1;
        float v1 = elv.y + erv.y + ew2.x * aew2 + ew2.y * aew3;
        v0 = v0 >= 0.f ? v0 : NEG_SLOPE * v0;
        v1 = v1 >= 0.f ? v1 : NEG_SLOPE * v1;
        float ee0 = __expf(v0);
        float ee1 = __expf(v1);
        int pos = atomicAdd(cursor + ((size_t)d << CSH), 1);
        if (pos < CAP) {
            unsigned pk = ((unsigned)f2bf(ee1) << 16) | (unsigned)f2bf(ee0);
            edata[(size_t)d * CAP + pos] = make_uint2((unsigned)s, pk);
        } else {
            int o = atomicAdd(ovfcnt, 1);
            if (o < OVFCAP)
                ovf[o] = make_float4(__int_as_float(d), __int_as_float(s), ee0, ee1);
        }
    }
}

// ---------- K2: wave-specialized fused gemm(ftb) || edge scatter ----------
// 512 threads. Waves 4-7: edge partition [0, ESPLIT) immediately after the
// staging barrier. Waves 0-3: gemm role (~15us), THEN join edge work on the
// back partition [ESPLIT, E) -- r8's counters (occ 16%, VALU 2.9%, FETCH
// 24MB, nothing saturated) showed the edge role is latency x wave-count
// bound, and half the block's waves were exiting after the gemm.
// ESPLIT = 5E/8 balances s*W = G + (1-s)*W with G~15us, W~66us.
__global__ __launch_bounds__(512) void fused_gemm_edge(
        const float* __restrict__ feat, const unsigned short* __restrict__ Wb,
        unsigned short* __restrict__ ftb,
        const float* __restrict__ el, const float* __restrict__ er,
        const float* __restrict__ e_w, const int* __restrict__ src,
        const int* __restrict__ dst, const float* __restrict__ attn_ew,
        int* __restrict__ cursor, int* __restrict__ ovfcnt,
        uint2* __restrict__ edata, float4* __restrict__ ovf,
        int N, int E) {
    __shared__ unsigned short Bs[256 * APITCH];   // 69,632 B -> 2 blocks/CU
    const int t = threadIdx.x;
    const int lane = t & 63;
    const int m16 = lane & 15, quad = lane >> 4;
    const int n0 = blockIdx.x * 128;
    const int ESPLIT = (E >> 3) * 5;              // 500k front / 300k back
    const int stride = gridDim.x * 256;
    const float aew0 = attn_ew[0], aew1 = attn_ew[1];
    const float aew2 = attn_ew[2], aew3 = attn_ew[3];

    frag_ab af[2][4];
    bool vr0 = false, vr1 = false;
    int r0n = 0, r1n = 0;
    if (t < 256) {   // gemm waves: A-frag loads (overlap staging below)
        const int w = t >> 6;
        r0n = n0 + w * 16 + m16;
        r1n = r0n + 64;
        vr0 = r0n < N; vr1 = r1n < N;
#pragma unroll
        for (int kc = 0; kc < 4; ++kc) {
            const int cc = kc * 32 + quad * 8;
            float4 ga0 = make_float4(0.f, 0.f, 0.f, 0.f), ga1 = ga0;
            float4 gb0 = ga0, gb1 = ga0;
            if (vr0) {
                ga0 = *(const float4*)(feat + (size_t)r0n * INF + cc);
                ga1 = *(const float4*)(feat + (size_t)r0n * INF + cc + 4);
            }
            if (vr1) {
                gb0 = *(const float4*)(feat + (size_t)r1n * INF + cc);
                gb1 = *(const float4*)(feat + (size_t)r1n * INF + cc + 4);
            }
            union { int4 i; frag_ab f; } ua, ub;
            ua.i.x = (int)cvt_pk_bf16(ga0.x, ga0.y); ua.i.y = (int)cvt_pk_bf16(ga0.z, ga0.w);
            ua.i.z = (int)cvt_pk_bf16(ga1.x, ga1.y); ua.i.w = (int)cvt_pk_bf16(ga1.z, ga1.w);
            ub.i.x = (int)cvt_pk_bf16(gb0.x, gb0.y); ub.i.y = (int)cvt_pk_bf16(gb0.z, gb0.w);
            ub.i.z = (int)cvt_pk_bf16(gb1.x, gb1.y); ub.i.w = (int)cvt_pk_bf16(gb1.z, gb1.w);
            af[0][kc] = ua.f; af[1][kc] = ub.f;
        }
    }

    // stage Wb -> Bs, all 512 threads: 4096 16B-chunks, 8 per thread
#pragma unroll
    for (int i = 0; i < 8; ++i) {
        int q = t + i * 512;
        int row = q >> 4, c = q & 15;
        ushort8v v = *(const ushort8v*)(Wb + row * 128 + c * 8);
        *(ushort8v*)(&Bs[row * APITCH + c * 8]) = v;
    }
    __syncthreads();   // Bs ready (single, uniformly-executed barrier)

    if (t < 256) {
        // ---------------- gemm role ----------------
#pragma unroll 1
        for (int jt = 0; jt < 4; ++jt) {
            frag_cd acc[2][4];
#pragma unroll
            for (int rg = 0; rg < 2; ++rg)
#pragma unroll
                for (int nt = 0; nt < 4; ++nt) acc[rg][nt] = frag_cd{0.f, 0.f, 0.f, 0.f};
#pragma unroll
            for (int kc = 0; kc < 4; ++kc)
#pragma unroll
                for (int nt = 0; nt < 4; ++nt) {
                    frag_ab bf = *(const frag_ab*)(&Bs[(jt * 64 + nt * 16 + m16) * APITCH
                                                       + kc * 32 + quad * 8]);
                    acc[0][nt] = __builtin_amdgcn_mfma_f32_16x16x32_bf16(bf, af[0][kc],
                                                                         acc[0][nt], 0, 0, 0);
                    acc[1][nt] = __builtin_amdgcn_mfma_f32_16x16x32_bf16(bf, af[1][kc],
                                                                         acc[1][nt], 0, 0, 0);
                }
            // lane holds j = jt*64 + nt*16 + quad*4 + (0..3) of its node row
#pragma unroll
            for (int rg = 0; rg < 2; ++rg) {
                const int rr = rg ? r1n : r0n;
                if (rg ? vr1 : vr0) {
#pragma unroll
                    for (int nt = 0; nt < 4; ++nt) {
                        uint2 p;
                        p.x = cvt_pk_bf16(acc[rg][nt][0], acc[rg][nt][1]);
                        p.y = cvt_pk_bf16(acc[rg][nt][2], acc[rg][nt][3]);
                        *(uint2*)(ftb + (size_t)rr * 256 + jt * 64 + nt * 16 + quad * 4) = p;
                    }
                }
            }
        }
        // ---------------- then join edge work: back partition ----------------
        edge_work(ESPLIT + blockIdx.x * 256 + t, E, stride,
                  el, er, e_w, src, dst, aew0, aew1, aew2, aew3,
                  cursor, ovfcnt, edata, ovf);
    } else {
        // ---------------- edge role: front partition ----------------
        edge_work(blockIdx.x * 256 + (t - 256), ESPLIT, stride,
                  el, er, e_w, src, dst, aew0, aew1, aew2, aew3,
                  cursor, ovfcnt, edata, ovf);
    }
}

// ---------- K3: wave-per-node gather-aggregate (EXACT r8 code, 65us proven) ----------
__global__ __launch_bounds__(256) void aggregate(const unsigned short* __restrict__ ftb,
                                                 const float* __restrict__ feat,
                                                 const uint2* __restrict__ edata,
                                                 const int* __restrict__ cursor,
                                                 const int* __restrict__ ovfcnt,
                                                 const float4* __restrict__ ovf,
                                                 float* __restrict__ out, int N) {
    const int t = threadIdx.x;
    const int w = t >> 6, l = t & 63;
    const int n = blockIdx.x * 4 + w;
    if (n >= N) return;
    const int c0 = 4 * l;            // this lane's 4 cols (0..252)
    const int h = l >> 5;            // lane's head
    const int cnt = cursor[(size_t)n << CSH];
    const int cmain = cnt < CAP ? cnt : CAP;
    const uint2* eb = edata + (size_t)n * CAP;

    float4 acc = make_float4(0.f, 0.f, 0.f, 0.f);
    float dn = 0.f;
#pragma unroll 4
    for (int i = 0; i < cmain; ++i) {
        uint2 rec = eb[i];
        int s = (int)rec.x;
        float a = bf2f((unsigned short)(h ? (rec.y >> 16) : (rec.y & 0xFFFFu)));
        dn += a;
        ushort4 v = *(const ushort4*)(ftb + (size_t)s * 256 + c0);
        acc.x += a * bf2f(v.x);
        acc.y += a * bf2f(v.y);
        acc.z += a * bf2f(v.z);
        acc.w += a * bf2f(v.w);
    }
    if (cnt > CAP) {   // exact overflow path (rare)
        int no = *ovfcnt; if (no > OVFCAP) no = OVFCAP;
        for (int i = 0; i < no; ++i) {
            float4 ov = ovf[i];
            if (__float_as_int(ov.x) == n) {
                int s = __float_as_int(ov.y);
                float a = h ? ov.w : ov.z;
                dn += a;
                ushort4 v = *(const ushort4*)(ftb + (size_t)s * 256 + c0);
                acc.x += a * bf2f(v.x);
                acc.y += a * bf2f(v.y);
                acc.z += a * bf2f(v.z);
                acc.w += a * bf2f(v.w);
            }
        }
    }
    float inv = dn > 0.f ? 1.0f / dn : 0.f;
    float4 f4 = *(const float4*)(feat + (size_t)n * INF + (c0 & 127));
    float4 r;
    r.x = acc.x * inv + f4.x;
    r.y = acc.y * inv + f4.y;
    r.z = acc.z * inv + f4.z;
    r.w = acc.w * inv + f4.w;
    r.x = r.x > 0.f ? r.x : expm1f(r.x);
    r.y = r.y > 0.f ? r.y : expm1f(r.y);
    r.z = r.z > 0.f ? r.z : expm1f(r.z);
    r.w = r.w > 0.f ? r.w : expm1f(r.w);
    *(float4*)(out + (size_t)n * 256 + c0) = r;
}

extern "C" void kernel_launch(void* const* d_in, const int* in_sizes, int n_in,
                              void* d_out, int out_size, void* d_ws, size_t ws_size,
                              hipStream_t stream) {
    const float* feat    = (const float*)d_in[0];
    const float* e_w     = (const float*)d_in[1];
    const int*   src     = (const int*)d_in[2];
    const int*   dst     = (const int*)d_in[3];
    const float* W       = (const float*)d_in[4];
    const float* attn_l  = (const float*)d_in[5];
    const float* attn_r  = (const float*)d_in[6];
    const float* attn_ew = (const float*)d_in[7];
    float* out = (float*)d_out;

    const int N = in_sizes[0] / INF;   // 50000
    const int E = in_sizes[2];         // 800000

    // workspace carve-up (all offsets 16B-aligned for these sizes; ~43 MB)
    unsigned short* ftb = (unsigned short*)d_ws;                 // N*256 bf16   (25.6 MB)
    uint2*  edata  = (uint2*)(ftb + (size_t)N * 256);            // N*CAP        (12.8 MB)
    float*  el     = (float*)(edata + (size_t)N * CAP);          // N*2          (0.4 MB)
    float*  er     = el + (size_t)N * 2;                         // N*2          (0.4 MB)
    float*  wfold  = er + (size_t)N * 2;                         // 4*128 f      (2 KB)
    unsigned short* Wb = (unsigned short*)(wfold + 512);         // 256*128 bf16 (64 KB)
    float4* ovf    = (float4*)(Wb + 32768);                      // OVFCAP       (0.5 MB)
    int*    cursor = (int*)(ovf + OVFCAP);                       // N*16 (64B-padded, 3.2 MB)
    int*    ovfcnt = cursor + ((size_t)N << CSH);                // 1

    init_kernel<<<9, 256, 0, stream>>>(W, attn_l, attn_r, Wb, wfold);

    prep_kernel<<<(N + 7) / 8, 256, 0, stream>>>(feat, wfold, el, er, cursor, ovfcnt, N);

    fused_gemm_edge<<<(N + 127) / 128, 512, 0, stream>>>(feat, Wb, ftb, el, er, e_w,
                                                         src, dst, attn_ew,
                                                         cursor, ovfcnt, edata, ovf, N, E);

    aggregate<<<(N + 3) / 4, 256, 0, stream>>>(ftb, feat, edata, cursor, ovfcnt, ovf, out, N);
}